// Round 11
// baseline (1200.580 us; speedup 1.0000x reference)
//
#include <hip/hip_runtime.h>
#include <hip/hip_bf16.h>
#include <hip/hip_cooperative_groups.h>
#include <cstdint>

namespace cg = cooperative_groups;

// Problem constants
#define BB 16
#define NN 4096
#define MM 1024
#define KNB 16
#define CIN 64
#define COUT 128
#define RTOT (BB*MM*KNB)   // 262144 rows
#define AP1 104            // gemm1 LDS row stride (96 used + 8 pad), bf16
#define AP2 136            // gemm2 LDS row stride (128 + 8 pad), bf16

typedef __attribute__((ext_vector_type(8))) short short8v;
typedef __attribute__((ext_vector_type(4))) float floatx4;

// ---------- helpers ----------
__device__ __forceinline__ float bflo(uint32_t u){ return __uint_as_float(u << 16); }
__device__ __forceinline__ float bfhi(uint32_t u){ return __uint_as_float(u & 0xffff0000u); }
__device__ __forceinline__ uint32_t f2bf_pk(float a, float b){
  uint32_t ua = __float_as_uint(a), ub = __float_as_uint(b);
  ua += 0x7fffu + ((ua >> 16) & 1u);   // RNE
  ub += 0x7fffu + ((ub >> 16) & 1u);
  return (ua >> 16) | (ub & 0xffff0000u);
}
__device__ __forceinline__ uint16_t f2bf1(float a){
  uint32_t u = __float_as_uint(a);
  u += 0x7fffu + ((u >> 16) & 1u);
  return (uint16_t)(u >> 16);
}

// ---------- LDS ----------
struct FpsS { float pc[NN*3]; float4 sel[MM]; float2 cand[2][32]; };      // 66048 B
struct TrS  { float t[64][65]; };                                         // 16640 B
struct ConsS{ uint16_t Bh1[128*AP1]; uint16_t AhD[128*AP2];
              int winq[8*16]; float ssum[128]; float ssq[128]; };         // 62976 B
union PreU  { FpsS fps; TrS tr; ConsS cons; };

// ================= K1: FPS producer (blocks 0-15) || prework + pipelined kNN+GEMM1
//                       consumers (blocks 16-255) =================
// v11: publish every 128 iters (8 agent-release drains instead of 16); consumer
// poll sleep 127 (~3.4us) to cut contested-line traffic. All arithmetic identical.
__global__ __launch_bounds__(512, 2) void k_pre2(
    const float* __restrict__ p1, const float* __restrict__ x1,
    const float* __restrict__ w1,
    float* __restrict__ outp2, float* __restrict__ p2w,
    float4* __restrict__ p1n, uint16_t* __restrict__ xtb, float* __restrict__ Sz,
    uint16_t* __restrict__ h1, float* __restrict__ S1,
    int* __restrict__ prog, int* __restrict__ prep_done)
{
  __shared__ PreU u;
  const int blk = blockIdx.x, tid = threadIdx.x;
  const int lane = tid & 63, wid = tid >> 6;

  if (blk < 16){
    // ---------------- FPS producer ----------------
    int b = blk;
    const float* pb = p1 + (size_t)b*NN*3;
    float4 f[6];
    const float4* src = (const float4*)(pb + tid*24);
    #pragma unroll
    for (int j=0;j<6;j++) f[j] = src[j];
    #pragma unroll
    for (int j=0;j<6;j++) *(float4*)(u.fps.pc + tid*24 + j*4) = f[j];
    const float* fa = (const float*)f;
    float px[8],py[8],pz[8],dist[8];
    #pragma unroll
    for (int j=0;j<8;j++){ px[j]=fa[3*j]; py[j]=fa[3*j+1]; pz[j]=fa[3*j+2]; dist[j]=1e10f; }
    __syncthreads();
    float cx = u.fps.pc[0], cy = u.fps.pc[1], cz = u.fps.pc[2];
    if (tid==64) u.fps.sel[0] = make_float4(cx, cy, cz, 0.f);
    int g0 = tid*8;

    #define DPP_STEP(ctrl) { \
      int ov_i = __builtin_amdgcn_update_dpp(__float_as_int(mval), __float_as_int(mval), (ctrl), 0xf, 0xf, false); \
      int oi   = __builtin_amdgcn_update_dpp(midx, midx, (ctrl), 0xf, 0xf, false); \
      float ov = __int_as_float(ov_i); \
      if (ov > mval || (ov == mval && oi < midx)){ mval = ov; midx = oi; } }

    for (int i=1;i<MM;i++){
      float nd[8];
      #pragma unroll
      for (int j=0;j<8;j++){
        float dx=__fsub_rn(px[j],cx), dy=__fsub_rn(py[j],cy), dz=__fsub_rn(pz[j],cz);
        float d = __fadd_rn(__fadd_rn(__fmul_rn(dx,dx),__fmul_rn(dy,dy)),__fmul_rn(dz,dz));
        nd[j] = fminf(dist[j], d); dist[j] = nd[j];
      }
      float tv[4]; int ti[4];
      #pragma unroll
      for (int j=0;j<4;j++){
        bool r = nd[2*j+1] > nd[2*j];
        tv[j] = r ? nd[2*j+1] : nd[2*j];
        ti[j] = g0 + 2*j + (r ? 1 : 0);
      }
      { bool r = tv[1] > tv[0]; tv[0] = r?tv[1]:tv[0]; ti[0] = r?ti[1]:ti[0]; }
      { bool r = tv[3] > tv[2]; tv[2] = r?tv[3]:tv[2]; ti[2] = r?ti[3]:ti[2]; }
      bool rr = tv[2] > tv[0];
      float mval = rr ? tv[2] : tv[0];
      int   midx = rr ? ti[2] : ti[0];
      DPP_STEP(0xB1); DPP_STEP(0x4E); DPP_STEP(0x124); DPP_STEP(0x128);
      int pbuf = i & 1;
      if ((lane & 15) == 0) u.fps.cand[pbuf][wid*4 + (lane>>4)] = make_float2(mval, __int_as_float(midx));
      __syncthreads();
      float2 c0 = u.fps.cand[pbuf][lane & 15];
      float2 c1 = u.fps.cand[pbuf][16 + (lane & 15)];
      mval = c0.x; midx = __float_as_int(c0.y);
      { if (c1.x > mval){ mval = c1.x; midx = __float_as_int(c1.y); } }
      DPP_STEP(0xB1); DPP_STEP(0x4E); DPP_STEP(0x124); DPP_STEP(0x128);
      cx = u.fps.pc[midx*3+0]; cy = u.fps.pc[midx*3+1]; cz = u.fps.pc[midx*3+2];
      if (tid==64) u.fps.sel[i] = make_float4(cx, cy, cz, 0.f);
      if ((i & 127) == 127 && wid == 1){
        #pragma unroll
        for (int rep=0;rep<2;rep++){
          int e = i - 127 + rep*64 + lane;
          float4 s = u.fps.sel[e];
          float n2 = __fadd_rn(__fadd_rn(__fmul_rn(s.x,s.x),__fmul_rn(s.y,s.y)),__fmul_rn(s.z,s.z));
          *(float4*)(p2w + ((size_t)b*MM + e)*4) = make_float4(s.x, s.y, s.z, n2);
        }
        if (lane == 0)
          __hip_atomic_store(&prog[b*16], i+1, __ATOMIC_RELEASE, __HIP_MEMORY_SCOPE_AGENT);
      }
    }
    #undef DPP_STEP
    __syncthreads();
    for (int e = tid; e < MM; e += 512){
      float4 s = u.fps.sel[e];
      float* o = outp2 + ((size_t)b*MM + e)*3;
      o[0]=s.x; o[1]=s.y; o[2]=s.z;
    }
  } else {
    // ---------------- prework ----------------
    for (int i = (blk-16)*512 + tid; i < 16384; i += 240*512) Sz[i] = 0.f;
    for (int i = (blk-16)*512 + tid; i < BB*NN; i += 240*512){
      float x = p1[(size_t)i*3+0], y = p1[(size_t)i*3+1], z = p1[(size_t)i*3+2];
      float n = __fadd_rn(__fadd_rn(__fmul_rn(x,x),__fmul_rn(y,y)),__fmul_rn(z,z));
      p1n[i] = make_float4(x,y,z,n);
    }
    for (int tile = blk-16; tile < 1024; tile += 240){
      int b = tile >> 6, n0 = (tile & 63)*64;
      __syncthreads();
      int c = tid >> 3, q = tid & 7;
      const float* src = x1 + ((size_t)(b*64 + c))*NN + n0 + q*8;
      float4 f0 = *(const float4*)src, f1 = *(const float4*)(src+4);
      u.tr.t[c][q*8+0]=f0.x; u.tr.t[c][q*8+1]=f0.y; u.tr.t[c][q*8+2]=f0.z; u.tr.t[c][q*8+3]=f0.w;
      u.tr.t[c][q*8+4]=f1.x; u.tr.t[c][q*8+5]=f1.y; u.tr.t[c][q*8+6]=f1.z; u.tr.t[c][q*8+7]=f1.w;
      __syncthreads();
      int n = tid >> 3;
      uint32_t* dst = (uint32_t*)(xtb + ((size_t)(b*NN + n0 + n))*64 + q*8);
      #pragma unroll
      for (int j=0;j<4;j++)
        dst[j] = f2bf_pk(u.tr.t[q*8+2*j][n], u.tr.t[q*8+2*j+1][n]);
    }
    __threadfence();
    __syncthreads();
    if (tid == 0) atomicAdd(prep_done, 1);
    // stage w1 -> Bh1 (K-perm [x(64)|rel(3)|0]); zero block stats (TrS dead; union switch)
    for (int e = tid; e < 128*96; e += 512){
      int o = e / 96, k = e - o*96;
      float v = (k < 64) ? w1[o*67 + 3 + k] : ((k < 67) ? w1[o*67 + (k-64)] : 0.f);
      u.cons.Bh1[o*AP1 + k] = f2bf1(v);
    }
    if (tid < 128){ u.cons.ssum[tid]=0.f; u.cons.ssq[tid]=0.f; }
    __syncthreads();
    // wait for all 240 prework blocks (p1n/xtb from other blocks)
    {
      int pv = 0, sp = 0;
      if (lane == 0) pv = __hip_atomic_load(prep_done, __ATOMIC_ACQUIRE, __HIP_MEMORY_SCOPE_AGENT);
      pv = __shfl(pv, 0);
      while (pv < 240 && sp < (1<<16)){
        __builtin_amdgcn_s_sleep(127);
        if (lane == 0) pv = __hip_atomic_load(prep_done, __ATOMIC_ACQUIRE, __HIP_MEMORY_SCOPE_AGENT);
        pv = __shfl(pv, 0); sp++;
      }
    }
    // ---------------- pipelined kNN + fused GEMM1, one query per wave-step ----------------
    int ml = lane & 15, quad = lane >> 4, seg = lane >> 4;
    int gw = (blk-16)*8 + wid;                 // [0,1920)
    for (int qi = gw; qi < BB*MM; qi += 1920){
      int b = qi & 15, m = qi >> 4;
      int q2 = b*MM + m;
      {
        int pv = 0, sp = 0;
        if (lane == 0) pv = __hip_atomic_load(&prog[b*16], __ATOMIC_ACQUIRE, __HIP_MEMORY_SCOPE_AGENT);
        pv = __shfl(pv, 0);
        while (pv <= m && sp < (1<<16)){
          __builtin_amdgcn_s_sleep(127);
          if (lane == 0) pv = __hip_atomic_load(&prog[b*16], __ATOMIC_ACQUIRE, __HIP_MEMORY_SCOPE_AGENT);
          pv = __shfl(pv, 0); sp++;
        }
      }
      const float4 qv = *(const float4*)(p2w + (size_t)q2*4);
      const float4* pbn = p1n + (size_t)b*NN;
      float bd[16]; int bi[16];
      #pragma unroll
      for (int s=0;s<16;s++){ bd[s] = 1e30f; bi[s] = 0; }
      float wv = 1e30f; int wslot = 0;

      #define KPROC(T, PV) { \
        float dot = fmaf(qv.z, (PV).z, fmaf(qv.y, (PV).y, __fmul_rn(qv.x, (PV).x))); \
        float d2 = __fsub_rn(__fadd_rn(qv.w, (PV).w), __fmul_rn(2.0f, dot)); \
        if (d2 < wv){ \
          int c = (T)*64 + lane; \
          _Pragma("unroll") \
          for (int s=0;s<16;s++) if (s==wslot){ bd[s]=d2; bi[s]=c; } \
          wv = bd[0]; wslot = 0; \
          _Pragma("unroll") \
          for (int s=1;s<16;s++) if (bd[s] > wv){ wv = bd[s]; wslot = s; } \
        } }

      float4 cur = pbn[lane];
      for (int t=0;t<63;t++){
        float4 nx = pbn[(t+1)*64 + lane];
        KPROC(t, cur);
        cur = nx;
      }
      KPROC(63, cur);
      #undef KPROC

      float lv = bd[0]; int ls = 0;
      #pragma unroll
      for (int s=1;s<16;s++) if (bd[s] < lv){ lv = bd[s]; ls = s; }
      for (int r=0;r<16;r++){
        float rv = lv; int rl = lane;
        #pragma unroll
        for (int off=32; off>=1; off>>=1){
          float ov = __shfl_xor(rv, off); int ol = __shfl_xor(rl, off);
          if (ov < rv || (ov == rv && ol < rl)){ rv = ov; rl = ol; }
        }
        if (lane == rl){
          int idx = 0;
          #pragma unroll
          for (int s=0;s<16;s++) if (s==ls) idx = bi[s];
          u.cons.winq[wid*16 + r] = idx;
          #pragma unroll
          for (int s=0;s<16;s++) if (s==ls) bd[s] = 1e30f;
          lv = bd[0]; ls = 0;
          #pragma unroll
          for (int s=1;s<16;s++) if (bd[s] < lv){ lv = bd[s]; ls = s; }
        }
      }
      // ---- fused GEMM1 for this query's 16 rows (wave-private LDS rows) ----
      int n = u.cons.winq[wid*16 + ml];        // same-wave DS order: winq writes done
      {
        const uint4* s4 = (const uint4*)(xtb + ((size_t)(b*NN + n))*64 + seg*16);
        uint4* d4 = (uint4*)(u.cons.AhD + (wid*16 + ml)*AP2 + seg*16);
        d4[0] = s4[0]; d4[1] = s4[1];
        if (seg == 0){
          const float* pp = p1 + ((size_t)(b*NN + n))*3;
          float rx = __fsub_rn(pp[0], qv.x);
          float ry = __fsub_rn(pp[1], qv.y);
          float rz = __fsub_rn(pp[2], qv.z);
          uint4* dr = (uint4*)(u.cons.AhD + (wid*16 + ml)*AP2 + 64);
          dr[0] = make_uint4(f2bf_pk(rx, ry), f2bf_pk(rz, 0.f), 0u, 0u);
          dr[1] = make_uint4(0u,0u,0u,0u);
          dr[2] = make_uint4(0u,0u,0u,0u);
          dr[3] = make_uint4(0u,0u,0u,0u);
        }
      }
      short8v af[3];
      #pragma unroll
      for (int kc=0;kc<3;kc++)
        af[kc] = *(const short8v*)(u.cons.AhD + (wid*16 + ml)*AP2 + kc*32 + quad*8);
      floatx4 acc[8];
      #pragma unroll
      for (int ct=0;ct<8;ct++) acc[ct] = (floatx4){0.f,0.f,0.f,0.f};
      #pragma unroll
      for (int ct=0;ct<8;ct++){
        #pragma unroll
        for (int kc=0;kc<3;kc++){
          short8v bf = *(const short8v*)(u.cons.Bh1 + (ct*16+ml)*AP1 + kc*32 + quad*8);
          acc[ct] = __builtin_amdgcn_mfma_f32_16x16x32_bf16(af[kc], bf, acc[ct], 0, 0, 0);
        }
      }
      float csum[8], csq[8];
      #pragma unroll
      for (int ct=0;ct<8;ct++){
        float a0=acc[ct][0], a1=acc[ct][1], a2=acc[ct][2], a3=acc[ct][3];
        float s = (a0+a1)+(a2+a3);
        float qq2 = (a0*a0+a1*a1)+(a2*a2+a3*a3);
        s += __shfl_xor(s,16);  s += __shfl_xor(s,32);
        qq2 += __shfl_xor(qq2,16); qq2 += __shfl_xor(qq2,32);
        csum[ct]=s; csq[ct]=qq2;
        #pragma unroll
        for (int r=0;r<4;r++)
          u.cons.AhD[(wid*16 + quad*4 + r)*AP2 + ct*16 + ml] = f2bf1(acc[ct][r]);
      }
      #pragma unroll
      for (int jj=0;jj<2;jj++){
        int ct = quad*2 + jj, col = ct*16 + ml;
        atomicAdd(&u.cons.ssum[col], csum[ct]);
        atomicAdd(&u.cons.ssq[col],  csq[ct]);
      }
      // coalesced h1 write of own 16 rows (reads after same-wave D writes)
      {
        const uint4* s4 = (const uint4*)(u.cons.AhD + (wid*16 + ml)*AP2 + seg*32);
        uint4* dst = (uint4*)(h1 + ((size_t)q2*16 + ml)*128 + seg*32);
        dst[0]=s4[0]; dst[1]=s4[1]; dst[2]=s4[2]; dst[3]=s4[3];
      }
    }
    __syncthreads();
    int cp = (blk & 31)*256;
    if (tid < 128){ atomicAdd(&S1[cp+tid], u.cons.ssum[tid]); atomicAdd(&S1[cp+128+tid], u.cons.ssq[tid]); }
  }
}

// ---------- K6: GEMM2 bf16 MFMA + fused k-pool extrema, barrier-free wave-private ----------
// 256 blocks x 8 waves; w2 staged once; each wave owns a private 16-row LDS slab and
// grid-strides over 8 m-groups with zero barriers in the loop (same-wave DS ordering).
__global__ __launch_bounds__(512, 2) void k_gemm2(const __hip_bfloat16* __restrict__ h1,
                                               const float* __restrict__ w2,
                                               const float* __restrict__ g1v, const float* __restrict__ b1v,
                                               const float* __restrict__ S1, float* __restrict__ S2,
                                               float* __restrict__ hmax, float* __restrict__ hmin){
  __shared__ uint16_t Bh[128*AP2];            // 34816 B
  __shared__ uint16_t Aw[8*16*AP2];           // 34816 B, 8 wave-private slabs
  __shared__ float scb[128], shb[128], ssum[128], ssq[128];
  int tid = threadIdx.x;
  const int lane = tid & 63, wid = tid >> 6;
  if (tid < 128){
    float s=0.f, q=0.f;
    for (int c=0;c<32;c++){ s += S1[c*256+tid]; q += S1[c*256+128+tid]; }
    float inv = 1.0f / (float)RTOT;
    float mean = s * inv;
    float var  = q * inv - mean*mean;
    float rs = 1.0f / sqrtf(var + 1e-5f);
    float scv = g1v[tid] * rs;
    scb[tid] = scv;
    shb[tid] = b1v[tid] - mean*scv;
    ssum[tid] = 0.f; ssq[tid] = 0.f;
  }
  {
    int o = tid >> 2, q4 = tid & 3;
    const float4* wr = (const float4*)(w2 + (size_t)o*128 + q4*32);
    uint32_t* bd = (uint32_t*)(Bh + o*AP2 + q4*32);
    #pragma unroll
    for (int j=0;j<8;j++){
      float4 v = wr[j];
      bd[2*j]   = f2bf_pk(v.x, v.y);
      bd[2*j+1] = f2bf_pk(v.z, v.w);
    }
  }
  __syncthreads();
  int ml = lane & 15, quad = lane >> 4;
  uint16_t* Amy = Aw + wid*16*AP2;
  for (int g = blockIdx.x*8 + wid; g < 16384; g += 2048){
    size_t r0 = (size_t)g*16;
    // stage 16 rows with bn1+relu (4 lanes per row, 32 cols each)
    {
      int row = lane >> 2, seg = lane & 3;
      const uint4* hp4 = (const uint4*)(h1 + (r0+row)*128 + seg*32);
      #pragma unroll
      for (int q=0;q<4;q++){
        uint4 uu = hp4[q];
        int cg = seg*32 + q*8;
        uint32_t wv4[4] = {uu.x,uu.y,uu.z,uu.w};
        uint32_t ov[4];
        #pragma unroll
        for (int t=0;t<4;t++){
          int c = cg + t*2;
          float a0 = fmaxf(fmaf(bflo(wv4[t]), scb[c],   shb[c]),   0.f);
          float a1 = fmaxf(fmaf(bfhi(wv4[t]), scb[c+1], shb[c+1]), 0.f);
          ov[t] = f2bf_pk(a0, a1);
        }
        *(uint4*)(Amy + row*AP2 + cg) = make_uint4(ov[0],ov[1],ov[2],ov[3]);
      }
    }
    // A frags from own slab (same-wave DS ordering: no barrier needed)
    short8v af[4];
    #pragma unroll
    for (int kc=0;kc<4;kc++)
      af[kc] = *(const short8v*)(Amy + ml*AP2 + kc*32 + quad*8);
    floatx4 acc[8];
    #pragma unroll
    for (int ct=0;ct<8;ct++) acc[ct] = (floatx4){0.f,0.f,0.f,0.f};
    #pragma unroll
    for (int ct=0;ct<8;ct++){
      #pragma unroll
      for (int kc=0;kc<4;kc++){
        short8v bf = *(const short8v*)(Bh + (ct*16+ml)*AP2 + kc*32 + quad*8);
        acc[ct] = __builtin_amdgcn_mfma_f32_16x16x32_bf16(af[kc], bf, acc[ct], 0, 0, 0);
      }
    }
    float cm[8], cn[8], cs[8], cq[8];
    #pragma unroll
    for (int ct=0;ct<8;ct++){
      float a0=acc[ct][0], a1=acc[ct][1], a2=acc[ct][2], a3=acc[ct][3];
      float mx = fmaxf(fmaxf(a0,a1), fmaxf(a2,a3));
      float mn = fminf(fminf(a0,a1), fminf(a2,a3));
      float s  = (a0+a1)+(a2+a3);
      float q2 = (a0*a0+a1*a1)+(a2*a2+a3*a3);
      mx = fmaxf(mx, __shfl_xor(mx,16)); mx = fmaxf(mx, __shfl_xor(mx,32));
      mn = fminf(mn, __shfl_xor(mn,16)); mn = fminf(mn, __shfl_xor(mn,32));
      s += __shfl_xor(s,16);  s += __shfl_xor(s,32);
      q2 += __shfl_xor(q2,16); q2 += __shfl_xor(q2,32);
      cm[ct]=mx; cn[ct]=mn; cs[ct]=s; cq[ct]=q2;
    }
    #pragma unroll
    for (int jj=0;jj<2;jj++){
      int ct = quad*2 + jj, col = ct*16 + ml;
      hmax[(size_t)g*128 + col] = cm[ct];
      hmin[(size_t)g*128 + col] = cn[ct];
      atomicAdd(&ssum[col], cs[ct]);
      atomicAdd(&ssq[col],  cq[ct]);
    }
  }
  __syncthreads();
  int cp = (blockIdx.x & 31)*256;
  if (tid < 128){ atomicAdd(&S2[cp+tid], ssum[tid]); atomicAdd(&S2[cp+128+tid], ssq[tid]); }
}

// ---------- K8: bn2+relu on pooled extrema (P2 computed per-block from S2) ----------
__global__ __launch_bounds__(256) void k_pool(const float* __restrict__ hmax, const float* __restrict__ hmin,
                                              const float* __restrict__ g2v, const float* __restrict__ b2v,
                                              const float* __restrict__ S2, float* __restrict__ out1){
  __shared__ float ot[128*65];
  __shared__ float scs[128], shs[128];
  int tid = threadIdx.x, blk = blockIdx.x;
  int b = blk >> 4, m0 = (blk & 15) * 64;
  if (tid < 128){
    float s=0.f, q=0.f;
    for (int c=0;c<32;c++){ s += S2[c*256+tid]; q += S2[c*256+128+tid]; }
    float inv = 1.0f / (float)RTOT;
    float mean = s * inv;
    float var  = q * inv - mean*mean;
    float rs = 1.0f / sqrtf(var + 1e-5f);
    float scv = g2v[tid] * rs;
    scs[tid] = scv;
    shs[tid] = b2v[tid] - mean*scv;
  }
  __syncthreads();
  int ml = tid >> 2, oq = tid & 3, o0 = oq*32;
  int gm = b*MM + m0 + ml;
  const float4* xr = (const float4*)(hmax + (size_t)gm*128 + o0);
  const float4* nr = (const float4*)(hmin + (size_t)gm*128 + o0);
  #pragma unroll
  for (int j2=0;j2<8;j2++){
    float4 hx = xr[j2], hn = nr[j2];
    float hv[4] = {hx.x, hx.y, hx.z, hx.w};
    float nv[4] = {hn.x, hn.y, hn.z, hn.w};
    #pragma unroll
    for (int e=0;e<4;e++){
      int c = o0 + j2*4 + e;
      float sc = scs[c], sh = shs[c];
      float h = (sc >= 0.f) ? hv[e] : nv[e];
      ot[c*65 + ml] = fmaxf(fmaf(h, sc, sh), 0.f);
    }
  }
  __syncthreads();
  int o = tid >> 1, mh = tid & 1;
  float* dst = out1 + ((size_t)(b*COUT + o))*MM + m0 + mh*32;
  #pragma unroll
  for (int j2=0;j2<8;j2++){
    float4 v;
    v.x=ot[o*65+mh*32+j2*4+0]; v.y=ot[o*65+mh*32+j2*4+1];
    v.z=ot[o*65+mh*32+j2*4+2]; v.w=ot[o*65+mh*32+j2*4+3];
    *(float4*)(dst + j2*4) = v;
  }
}

extern "C" void kernel_launch(void* const* d_in, const int* in_sizes, int n_in,
                              void* d_out, int out_size, void* d_ws, size_t ws_size,
                              hipStream_t stream) {
  (void)in_sizes; (void)n_in; (void)out_size; (void)ws_size;
  const float* p1 = (const float*)d_in[0];
  const float* x1 = (const float*)d_in[1];
  const float* w1 = (const float*)d_in[2];
  const float* g1 = (const float*)d_in[3];
  const float* b1 = (const float*)d_in[4];
  const float* w2 = (const float*)d_in[5];
  const float* g2 = (const float*)d_in[6];
  const float* b2 = (const float*)d_in[7];
  float* out = (float*)d_out;
  float* ws  = (float*)d_ws;

  // ws map (float indices)
  uint16_t* xtb = (uint16_t*)ws;                    // [B,N,64] bf16
  float4* p1n   = (float4*)(ws + 2097152);          // [B,N]
  float*  p2w   = ws + 2621440;                     // [B,M,4]
  float*  S1    = ws + 2686976;                     // 8192
  float*  S2    = ws + 2695168;                     // 8192
  uint16_t* h1  = (uint16_t*)(ws + 2703872);        // [R,128] bf16
  float*  hmax  = ws + 19481088;                    // [B*M,128]
  float*  hmin  = ws + 21578240;                    // [B*M,128]
  int*    prog  = (int*)(ws + 23675392);            // 16 batches x stride 16
  int*    prep_done = (int*)(ws + 23675392) + 256;
  float*  outp2 = out;                              // [B,M,3]
  float*  out1  = out + 49152;                      // [B,128,M]

  hipMemsetAsync(prog, 0, 2048, stream);            // prog + prep_done

  void* args[] = { (void*)&p1, (void*)&x1, (void*)&w1,
                   (void*)&outp2, (void*)&p2w,
                   (void*)&p1n, (void*)&xtb, (void*)&S1,
                   (void*)&h1, (void*)&S1, (void*)&prog, (void*)&prep_done };
  hipLaunchCooperativeKernel((void*)k_pre2, dim3(256), dim3(512), args, 0, stream);

  k_gemm2<<<256, 512, 0, stream>>>((const __hip_bfloat16*)h1, w2, g1, b1, S1, S2, hmax, hmin);
  k_pool<<<256, 256, 0, stream>>>(hmax, hmin, g2, b2, S2, out1);
}

// Round 12
// 1175.395 us; speedup vs baseline: 1.0214x; 1.0214x over previous
//
#include <hip/hip_runtime.h>
#include <hip/hip_bf16.h>
#include <hip/hip_cooperative_groups.h>
#include <cstdint>

namespace cg = cooperative_groups;

// Problem constants
#define BB 16
#define NN 4096
#define MM 1024
#define KNB 16
#define CIN 64
#define COUT 128
#define RTOT (BB*MM*KNB)   // 262144 rows
#define AP1 104            // gemm1 LDS row stride (96 used + 8 pad), bf16
#define AP2 136            // gemm2 LDS row stride (128 + 8 pad), bf16

typedef __attribute__((ext_vector_type(8))) short short8v;
typedef __attribute__((ext_vector_type(4))) float floatx4;

// ---------- helpers ----------
__device__ __forceinline__ float bflo(uint32_t u){ return __uint_as_float(u << 16); }
__device__ __forceinline__ float bfhi(uint32_t u){ return __uint_as_float(u & 0xffff0000u); }
__device__ __forceinline__ uint32_t f2bf_pk(float a, float b){
  uint32_t ua = __float_as_uint(a), ub = __float_as_uint(b);
  ua += 0x7fffu + ((ua >> 16) & 1u);   // RNE
  ub += 0x7fffu + ((ub >> 16) & 1u);
  return (ua >> 16) | (ub & 0xffff0000u);
}
__device__ __forceinline__ uint16_t f2bf1(float a){
  uint32_t u = __float_as_uint(a);
  u += 0x7fffu + ((u >> 16) & 1u);
  return (uint16_t)(u >> 16);
}

// ---------- LDS ----------
struct FpsS { float pc[NN*3]; float4 sel[MM]; float2 cand[2][32]; };      // 66048 B
struct TrS  { float t[64][65]; };                                         // 16640 B
struct ConsS{ uint16_t Bh1[128*AP1]; uint16_t AhD[128*AP2];
              int winq[8*16]; float ssum[128]; float ssq[128]; };         // 62976 B
union PreU  { FpsS fps; TrS tr; ConsS cons; };

// ================= K1: FPS producer (blocks 0-15) || prework + pipelined kNN+GEMM1
//                       consumers (blocks 16-255) =================
// v12: publish every 64 iters (round-10 cadence, best measured) with DEFERRED
// release: wave 1 stores the 64 p2w entries at i&63==63, and publishes the flag
// at the NEXT iteration (i&63==0, value i) — by then the stores have drained
// during ~0.9us of compute, so the release's vmcnt(0) is near-free. Final flag
// (1024) after the loop. Consumer sleep back to 64. All arithmetic identical.
__global__ __launch_bounds__(512, 2) void k_pre2(
    const float* __restrict__ p1, const float* __restrict__ x1,
    const float* __restrict__ w1,
    float* __restrict__ outp2, float* __restrict__ p2w,
    float4* __restrict__ p1n, uint16_t* __restrict__ xtb, float* __restrict__ Sz,
    uint16_t* __restrict__ h1, float* __restrict__ S1,
    int* __restrict__ prog, int* __restrict__ prep_done)
{
  __shared__ PreU u;
  const int blk = blockIdx.x, tid = threadIdx.x;
  const int lane = tid & 63, wid = tid >> 6;

  if (blk < 16){
    // ---------------- FPS producer ----------------
    int b = blk;
    const float* pb = p1 + (size_t)b*NN*3;
    float4 f[6];
    const float4* src = (const float4*)(pb + tid*24);
    #pragma unroll
    for (int j=0;j<6;j++) f[j] = src[j];
    #pragma unroll
    for (int j=0;j<6;j++) *(float4*)(u.fps.pc + tid*24 + j*4) = f[j];
    const float* fa = (const float*)f;
    float px[8],py[8],pz[8],dist[8];
    #pragma unroll
    for (int j=0;j<8;j++){ px[j]=fa[3*j]; py[j]=fa[3*j+1]; pz[j]=fa[3*j+2]; dist[j]=1e10f; }
    __syncthreads();
    float cx = u.fps.pc[0], cy = u.fps.pc[1], cz = u.fps.pc[2];
    if (tid==64) u.fps.sel[0] = make_float4(cx, cy, cz, 0.f);
    int g0 = tid*8;

    #define DPP_STEP(ctrl) { \
      int ov_i = __builtin_amdgcn_update_dpp(__float_as_int(mval), __float_as_int(mval), (ctrl), 0xf, 0xf, false); \
      int oi   = __builtin_amdgcn_update_dpp(midx, midx, (ctrl), 0xf, 0xf, false); \
      float ov = __int_as_float(ov_i); \
      if (ov > mval || (ov == mval && oi < midx)){ mval = ov; midx = oi; } }

    for (int i=1;i<MM;i++){
      float nd[8];
      #pragma unroll
      for (int j=0;j<8;j++){
        float dx=__fsub_rn(px[j],cx), dy=__fsub_rn(py[j],cy), dz=__fsub_rn(pz[j],cz);
        float d = __fadd_rn(__fadd_rn(__fmul_rn(dx,dx),__fmul_rn(dy,dy)),__fmul_rn(dz,dz));
        nd[j] = fminf(dist[j], d); dist[j] = nd[j];
      }
      float tv[4]; int ti[4];
      #pragma unroll
      for (int j=0;j<4;j++){
        bool r = nd[2*j+1] > nd[2*j];
        tv[j] = r ? nd[2*j+1] : nd[2*j];
        ti[j] = g0 + 2*j + (r ? 1 : 0);
      }
      { bool r = tv[1] > tv[0]; tv[0] = r?tv[1]:tv[0]; ti[0] = r?ti[1]:ti[0]; }
      { bool r = tv[3] > tv[2]; tv[2] = r?tv[3]:tv[2]; ti[2] = r?ti[3]:ti[2]; }
      bool rr = tv[2] > tv[0];
      float mval = rr ? tv[2] : tv[0];
      int   midx = rr ? ti[2] : ti[0];
      DPP_STEP(0xB1); DPP_STEP(0x4E); DPP_STEP(0x124); DPP_STEP(0x128);
      int pbuf = i & 1;
      if ((lane & 15) == 0) u.fps.cand[pbuf][wid*4 + (lane>>4)] = make_float2(mval, __int_as_float(midx));
      __syncthreads();
      float2 c0 = u.fps.cand[pbuf][lane & 15];
      float2 c1 = u.fps.cand[pbuf][16 + (lane & 15)];
      mval = c0.x; midx = __float_as_int(c0.y);
      { if (c1.x > mval){ mval = c1.x; midx = __float_as_int(c1.y); } }
      DPP_STEP(0xB1); DPP_STEP(0x4E); DPP_STEP(0x124); DPP_STEP(0x128);
      cx = u.fps.pc[midx*3+0]; cy = u.fps.pc[midx*3+1]; cz = u.fps.pc[midx*3+2];
      if (tid==64) u.fps.sel[i] = make_float4(cx, cy, cz, 0.f);
      if (wid == 1){
        if ((i & 63) == 63){
          // store batch [i-63, i]; do NOT publish yet (let stores drain during compute)
          int e = i - 63 + lane;
          float4 s = u.fps.sel[e];
          float n2 = __fadd_rn(__fadd_rn(__fmul_rn(s.x,s.x),__fmul_rn(s.y,s.y)),__fmul_rn(s.z,s.z));
          *(float4*)(p2w + ((size_t)b*MM + e)*4) = make_float4(s.x, s.y, s.z, n2);
        }
        if ((i & 63) == 0 && lane == 0){
          // deferred release: covers entries < i (stored last flush, long drained)
          __hip_atomic_store(&prog[b*16], i, __ATOMIC_RELEASE, __HIP_MEMORY_SCOPE_AGENT);
        }
      }
    }
    #undef DPP_STEP
    if (tid == 64)
      __hip_atomic_store(&prog[b*16], MM, __ATOMIC_RELEASE, __HIP_MEMORY_SCOPE_AGENT);
    __syncthreads();
    for (int e = tid; e < MM; e += 512){
      float4 s = u.fps.sel[e];
      float* o = outp2 + ((size_t)b*MM + e)*3;
      o[0]=s.x; o[1]=s.y; o[2]=s.z;
    }
  } else {
    // ---------------- prework ----------------
    for (int i = (blk-16)*512 + tid; i < 16384; i += 240*512) Sz[i] = 0.f;
    for (int i = (blk-16)*512 + tid; i < BB*NN; i += 240*512){
      float x = p1[(size_t)i*3+0], y = p1[(size_t)i*3+1], z = p1[(size_t)i*3+2];
      float n = __fadd_rn(__fadd_rn(__fmul_rn(x,x),__fmul_rn(y,y)),__fmul_rn(z,z));
      p1n[i] = make_float4(x,y,z,n);
    }
    for (int tile = blk-16; tile < 1024; tile += 240){
      int b = tile >> 6, n0 = (tile & 63)*64;
      __syncthreads();
      int c = tid >> 3, q = tid & 7;
      const float* src = x1 + ((size_t)(b*64 + c))*NN + n0 + q*8;
      float4 f0 = *(const float4*)src, f1 = *(const float4*)(src+4);
      u.tr.t[c][q*8+0]=f0.x; u.tr.t[c][q*8+1]=f0.y; u.tr.t[c][q*8+2]=f0.z; u.tr.t[c][q*8+3]=f0.w;
      u.tr.t[c][q*8+4]=f1.x; u.tr.t[c][q*8+5]=f1.y; u.tr.t[c][q*8+6]=f1.z; u.tr.t[c][q*8+7]=f1.w;
      __syncthreads();
      int n = tid >> 3;
      uint32_t* dst = (uint32_t*)(xtb + ((size_t)(b*NN + n0 + n))*64 + q*8);
      #pragma unroll
      for (int j=0;j<4;j++)
        dst[j] = f2bf_pk(u.tr.t[q*8+2*j][n], u.tr.t[q*8+2*j+1][n]);
    }
    __threadfence();
    __syncthreads();
    if (tid == 0) atomicAdd(prep_done, 1);
    // stage w1 -> Bh1 (K-perm [x(64)|rel(3)|0]); zero block stats (TrS dead; union switch)
    for (int e = tid; e < 128*96; e += 512){
      int o = e / 96, k = e - o*96;
      float v = (k < 64) ? w1[o*67 + 3 + k] : ((k < 67) ? w1[o*67 + (k-64)] : 0.f);
      u.cons.Bh1[o*AP1 + k] = f2bf1(v);
    }
    if (tid < 128){ u.cons.ssum[tid]=0.f; u.cons.ssq[tid]=0.f; }
    __syncthreads();
    // wait for all 240 prework blocks (p1n/xtb from other blocks)
    {
      int pv = 0, sp = 0;
      if (lane == 0) pv = __hip_atomic_load(prep_done, __ATOMIC_ACQUIRE, __HIP_MEMORY_SCOPE_AGENT);
      pv = __shfl(pv, 0);
      while (pv < 240 && sp < (1<<18)){
        __builtin_amdgcn_s_sleep(64);
        if (lane == 0) pv = __hip_atomic_load(prep_done, __ATOMIC_ACQUIRE, __HIP_MEMORY_SCOPE_AGENT);
        pv = __shfl(pv, 0); sp++;
      }
    }
    // ---------------- pipelined kNN + fused GEMM1, one query per wave-step ----------------
    int ml = lane & 15, quad = lane >> 4, seg = lane >> 4;
    int gw = (blk-16)*8 + wid;                 // [0,1920)
    for (int qi = gw; qi < BB*MM; qi += 1920){
      int b = qi & 15, m = qi >> 4;
      int q2 = b*MM + m;
      {
        int pv = 0, sp = 0;
        if (lane == 0) pv = __hip_atomic_load(&prog[b*16], __ATOMIC_ACQUIRE, __HIP_MEMORY_SCOPE_AGENT);
        pv = __shfl(pv, 0);
        while (pv <= m && sp < (1<<18)){
          __builtin_amdgcn_s_sleep(64);
          if (lane == 0) pv = __hip_atomic_load(&prog[b*16], __ATOMIC_ACQUIRE, __HIP_MEMORY_SCOPE_AGENT);
          pv = __shfl(pv, 0); sp++;
        }
      }
      const float4 qv = *(const float4*)(p2w + (size_t)q2*4);
      const float4* pbn = p1n + (size_t)b*NN;
      float bd[16]; int bi[16];
      #pragma unroll
      for (int s=0;s<16;s++){ bd[s] = 1e30f; bi[s] = 0; }
      float wv = 1e30f; int wslot = 0;

      #define KPROC(T, PV) { \
        float dot = fmaf(qv.z, (PV).z, fmaf(qv.y, (PV).y, __fmul_rn(qv.x, (PV).x))); \
        float d2 = __fsub_rn(__fadd_rn(qv.w, (PV).w), __fmul_rn(2.0f, dot)); \
        if (d2 < wv){ \
          int c = (T)*64 + lane; \
          _Pragma("unroll") \
          for (int s=0;s<16;s++) if (s==wslot){ bd[s]=d2; bi[s]=c; } \
          wv = bd[0]; wslot = 0; \
          _Pragma("unroll") \
          for (int s=1;s<16;s++) if (bd[s] > wv){ wv = bd[s]; wslot = s; } \
        } }

      float4 cur = pbn[lane];
      for (int t=0;t<63;t++){
        float4 nx = pbn[(t+1)*64 + lane];
        KPROC(t, cur);
        cur = nx;
      }
      KPROC(63, cur);
      #undef KPROC

      float lv = bd[0]; int ls = 0;
      #pragma unroll
      for (int s=1;s<16;s++) if (bd[s] < lv){ lv = bd[s]; ls = s; }
      for (int r=0;r<16;r++){
        float rv = lv; int rl = lane;
        #pragma unroll
        for (int off=32; off>=1; off>>=1){
          float ov = __shfl_xor(rv, off); int ol = __shfl_xor(rl, off);
          if (ov < rv || (ov == rv && ol < rl)){ rv = ov; rl = ol; }
        }
        if (lane == rl){
          int idx = 0;
          #pragma unroll
          for (int s=0;s<16;s++) if (s==ls) idx = bi[s];
          u.cons.winq[wid*16 + r] = idx;
          #pragma unroll
          for (int s=0;s<16;s++) if (s==ls) bd[s] = 1e30f;
          lv = bd[0]; ls = 0;
          #pragma unroll
          for (int s=1;s<16;s++) if (bd[s] < lv){ lv = bd[s]; ls = s; }
        }
      }
      // ---- fused GEMM1 for this query's 16 rows (wave-private LDS rows) ----
      int n = u.cons.winq[wid*16 + ml];        // same-wave DS order: winq writes done
      {
        const uint4* s4 = (const uint4*)(xtb + ((size_t)(b*NN + n))*64 + seg*16);
        uint4* d4 = (uint4*)(u.cons.AhD + (wid*16 + ml)*AP2 + seg*16);
        d4[0] = s4[0]; d4[1] = s4[1];
        if (seg == 0){
          const float* pp = p1 + ((size_t)(b*NN + n))*3;
          float rx = __fsub_rn(pp[0], qv.x);
          float ry = __fsub_rn(pp[1], qv.y);
          float rz = __fsub_rn(pp[2], qv.z);
          uint4* dr = (uint4*)(u.cons.AhD + (wid*16 + ml)*AP2 + 64);
          dr[0] = make_uint4(f2bf_pk(rx, ry), f2bf_pk(rz, 0.f), 0u, 0u);
          dr[1] = make_uint4(0u,0u,0u,0u);
          dr[2] = make_uint4(0u,0u,0u,0u);
          dr[3] = make_uint4(0u,0u,0u,0u);
        }
      }
      short8v af[3];
      #pragma unroll
      for (int kc=0;kc<3;kc++)
        af[kc] = *(const short8v*)(u.cons.AhD + (wid*16 + ml)*AP2 + kc*32 + quad*8);
      floatx4 acc[8];
      #pragma unroll
      for (int ct=0;ct<8;ct++) acc[ct] = (floatx4){0.f,0.f,0.f,0.f};
      #pragma unroll
      for (int ct=0;ct<8;ct++){
        #pragma unroll
        for (int kc=0;kc<3;kc++){
          short8v bf = *(const short8v*)(u.cons.Bh1 + (ct*16+ml)*AP1 + kc*32 + quad*8);
          acc[ct] = __builtin_amdgcn_mfma_f32_16x16x32_bf16(af[kc], bf, acc[ct], 0, 0, 0);
        }
      }
      float csum[8], csq[8];
      #pragma unroll
      for (int ct=0;ct<8;ct++){
        float a0=acc[ct][0], a1=acc[ct][1], a2=acc[ct][2], a3=acc[ct][3];
        float s = (a0+a1)+(a2+a3);
        float qq2 = (a0*a0+a1*a1)+(a2*a2+a3*a3);
        s += __shfl_xor(s,16);  s += __shfl_xor(s,32);
        qq2 += __shfl_xor(qq2,16); qq2 += __shfl_xor(qq2,32);
        csum[ct]=s; csq[ct]=qq2;
        #pragma unroll
        for (int r=0;r<4;r++)
          u.cons.AhD[(wid*16 + quad*4 + r)*AP2 + ct*16 + ml] = f2bf1(acc[ct][r]);
      }
      #pragma unroll
      for (int jj=0;jj<2;jj++){
        int ct = quad*2 + jj, col = ct*16 + ml;
        atomicAdd(&u.cons.ssum[col], csum[ct]);
        atomicAdd(&u.cons.ssq[col],  csq[ct]);
      }
      // coalesced h1 write of own 16 rows (reads after same-wave D writes)
      {
        const uint4* s4 = (const uint4*)(u.cons.AhD + (wid*16 + ml)*AP2 + seg*32);
        uint4* dst = (uint4*)(h1 + ((size_t)q2*16 + ml)*128 + seg*32);
        dst[0]=s4[0]; dst[1]=s4[1]; dst[2]=s4[2]; dst[3]=s4[3];
      }
    }
    __syncthreads();
    int cp = (blk & 31)*256;
    if (tid < 128){ atomicAdd(&S1[cp+tid], u.cons.ssum[tid]); atomicAdd(&S1[cp+128+tid], u.cons.ssq[tid]); }
  }
}

// ---------- K6: GEMM2 bf16 MFMA + fused k-pool extrema, barrier-free wave-private ----------
__global__ __launch_bounds__(512, 2) void k_gemm2(const __hip_bfloat16* __restrict__ h1,
                                               const float* __restrict__ w2,
                                               const float* __restrict__ g1v, const float* __restrict__ b1v,
                                               const float* __restrict__ S1, float* __restrict__ S2,
                                               float* __restrict__ hmax, float* __restrict__ hmin){
  __shared__ uint16_t Bh[128*AP2];            // 34816 B
  __shared__ uint16_t Aw[8*16*AP2];           // 34816 B, 8 wave-private slabs
  __shared__ float scb[128], shb[128], ssum[128], ssq[128];
  int tid = threadIdx.x;
  const int lane = tid & 63, wid = tid >> 6;
  if (tid < 128){
    float s=0.f, q=0.f;
    for (int c=0;c<32;c++){ s += S1[c*256+tid]; q += S1[c*256+128+tid]; }
    float inv = 1.0f / (float)RTOT;
    float mean = s * inv;
    float var  = q * inv - mean*mean;
    float rs = 1.0f / sqrtf(var + 1e-5f);
    float scv = g1v[tid] * rs;
    scb[tid] = scv;
    shb[tid] = b1v[tid] - mean*scv;
    ssum[tid] = 0.f; ssq[tid] = 0.f;
  }
  {
    int o = tid >> 2, q4 = tid & 3;
    const float4* wr = (const float4*)(w2 + (size_t)o*128 + q4*32);
    uint32_t* bd = (uint32_t*)(Bh + o*AP2 + q4*32);
    #pragma unroll
    for (int j=0;j<8;j++){
      float4 v = wr[j];
      bd[2*j]   = f2bf_pk(v.x, v.y);
      bd[2*j+1] = f2bf_pk(v.z, v.w);
    }
  }
  __syncthreads();
  int ml = lane & 15, quad = lane >> 4;
  uint16_t* Amy = Aw + wid*16*AP2;
  for (int g = blockIdx.x*8 + wid; g < 16384; g += 2048){
    size_t r0 = (size_t)g*16;
    {
      int row = lane >> 2, seg = lane & 3;
      const uint4* hp4 = (const uint4*)(h1 + (r0+row)*128 + seg*32);
      #pragma unroll
      for (int q=0;q<4;q++){
        uint4 uu = hp4[q];
        int cg = seg*32 + q*8;
        uint32_t wv4[4] = {uu.x,uu.y,uu.z,uu.w};
        uint32_t ov[4];
        #pragma unroll
        for (int t=0;t<4;t++){
          int c = cg + t*2;
          float a0 = fmaxf(fmaf(bflo(wv4[t]), scb[c],   shb[c]),   0.f);
          float a1 = fmaxf(fmaf(bfhi(wv4[t]), scb[c+1], shb[c+1]), 0.f);
          ov[t] = f2bf_pk(a0, a1);
        }
        *(uint4*)(Amy + row*AP2 + cg) = make_uint4(ov[0],ov[1],ov[2],ov[3]);
      }
    }
    short8v af[4];
    #pragma unroll
    for (int kc=0;kc<4;kc++)
      af[kc] = *(const short8v*)(Amy + ml*AP2 + kc*32 + quad*8);
    floatx4 acc[8];
    #pragma unroll
    for (int ct=0;ct<8;ct++) acc[ct] = (floatx4){0.f,0.f,0.f,0.f};
    #pragma unroll
    for (int ct=0;ct<8;ct++){
      #pragma unroll
      for (int kc=0;kc<4;kc++){
        short8v bf = *(const short8v*)(Bh + (ct*16+ml)*AP2 + kc*32 + quad*8);
        acc[ct] = __builtin_amdgcn_mfma_f32_16x16x32_bf16(af[kc], bf, acc[ct], 0, 0, 0);
      }
    }
    float cm[8], cn[8], cs[8], cq[8];
    #pragma unroll
    for (int ct=0;ct<8;ct++){
      float a0=acc[ct][0], a1=acc[ct][1], a2=acc[ct][2], a3=acc[ct][3];
      float mx = fmaxf(fmaxf(a0,a1), fmaxf(a2,a3));
      float mn = fminf(fminf(a0,a1), fminf(a2,a3));
      float s  = (a0+a1)+(a2+a3);
      float q2 = (a0*a0+a1*a1)+(a2*a2+a3*a3);
      mx = fmaxf(mx, __shfl_xor(mx,16)); mx = fmaxf(mx, __shfl_xor(mx,32));
      mn = fminf(mn, __shfl_xor(mn,16)); mn = fminf(mn, __shfl_xor(mn,32));
      s += __shfl_xor(s,16);  s += __shfl_xor(s,32);
      q2 += __shfl_xor(q2,16); q2 += __shfl_xor(q2,32);
      cm[ct]=mx; cn[ct]=mn; cs[ct]=s; cq[ct]=q2;
    }
    #pragma unroll
    for (int jj=0;jj<2;jj++){
      int ct = quad*2 + jj, col = ct*16 + ml;
      hmax[(size_t)g*128 + col] = cm[ct];
      hmin[(size_t)g*128 + col] = cn[ct];
      atomicAdd(&ssum[col], cs[ct]);
      atomicAdd(&ssq[col],  cq[ct]);
    }
  }
  __syncthreads();
  int cp = (blockIdx.x & 31)*256;
  if (tid < 128){ atomicAdd(&S2[cp+tid], ssum[tid]); atomicAdd(&S2[cp+128+tid], ssq[tid]); }
}

// ---------- K8: bn2+relu on pooled extrema (P2 computed per-block from S2) ----------
__global__ __launch_bounds__(256) void k_pool(const float* __restrict__ hmax, const float* __restrict__ hmin,
                                              const float* __restrict__ g2v, const float* __restrict__ b2v,
                                              const float* __restrict__ S2, float* __restrict__ out1){
  __shared__ float ot[128*65];
  __shared__ float scs[128], shs[128];
  int tid = threadIdx.x, blk = blockIdx.x;
  int b = blk >> 4, m0 = (blk & 15) * 64;
  if (tid < 128){
    float s=0.f, q=0.f;
    for (int c=0;c<32;c++){ s += S2[c*256+tid]; q += S2[c*256+128+tid]; }
    float inv = 1.0f / (float)RTOT;
    float mean = s * inv;
    float var  = q * inv - mean*mean;
    float rs = 1.0f / sqrtf(var + 1e-5f);
    float scv = g2v[tid] * rs;
    scs[tid] = scv;
    shs[tid] = b2v[tid] - mean*scv;
  }
  __syncthreads();
  int ml = tid >> 2, oq = tid & 3, o0 = oq*32;
  int gm = b*MM + m0 + ml;
  const float4* xr = (const float4*)(hmax + (size_t)gm*128 + o0);
  const float4* nr = (const float4*)(hmin + (size_t)gm*128 + o0);
  #pragma unroll
  for (int j2=0;j2<8;j2++){
    float4 hx = xr[j2], hn = nr[j2];
    float hv[4] = {hx.x, hx.y, hx.z, hx.w};
    float nv[4] = {hn.x, hn.y, hn.z, hn.w};
    #pragma unroll
    for (int e=0;e<4;e++){
      int c = o0 + j2*4 + e;
      float sc = scs[c], sh = shs[c];
      float h = (sc >= 0.f) ? hv[e] : nv[e];
      ot[c*65 + ml] = fmaxf(fmaf(h, sc, sh), 0.f);
    }
  }
  __syncthreads();
  int o = tid >> 1, mh = tid & 1;
  float* dst = out1 + ((size_t)(b*COUT + o))*MM + m0 + mh*32;
  #pragma unroll
  for (int j2=0;j2<8;j2++){
    float4 v;
    v.x=ot[o*65+mh*32+j2*4+0]; v.y=ot[o*65+mh*32+j2*4+1];
    v.z=ot[o*65+mh*32+j2*4+2]; v.w=ot[o*65+mh*32+j2*4+3];
    *(float4*)(dst + j2*4) = v;
  }
}

extern "C" void kernel_launch(void* const* d_in, const int* in_sizes, int n_in,
                              void* d_out, int out_size, void* d_ws, size_t ws_size,
                              hipStream_t stream) {
  (void)in_sizes; (void)n_in; (void)out_size; (void)ws_size;
  const float* p1 = (const float*)d_in[0];
  const float* x1 = (const float*)d_in[1];
  const float* w1 = (const float*)d_in[2];
  const float* g1 = (const float*)d_in[3];
  const float* b1 = (const float*)d_in[4];
  const float* w2 = (const float*)d_in[5];
  const float* g2 = (const float*)d_in[6];
  const float* b2 = (const float*)d_in[7];
  float* out = (float*)d_out;
  float* ws  = (float*)d_ws;

  // ws map (float indices)
  uint16_t* xtb = (uint16_t*)ws;                    // [B,N,64] bf16
  float4* p1n   = (float4*)(ws + 2097152);          // [B,N]
  float*  p2w   = ws + 2621440;                     // [B,M,4]
  float*  S1    = ws + 2686976;                     // 8192
  float*  S2    = ws + 2695168;                     // 8192
  uint16_t* h1  = (uint16_t*)(ws + 2703872);        // [R,128] bf16
  float*  hmax  = ws + 19481088;                    // [B*M,128]
  float*  hmin  = ws + 21578240;                    // [B*M,128]
  int*    prog  = (int*)(ws + 23675392);            // 16 batches x stride 16
  int*    prep_done = (int*)(ws + 23675392) + 256;
  float*  outp2 = out;                              // [B,M,3]
  float*  out1  = out + 49152;                      // [B,128,M]

  hipMemsetAsync(prog, 0, 2048, stream);            // prog + prep_done

  void* args[] = { (void*)&p1, (void*)&x1, (void*)&w1,
                   (void*)&outp2, (void*)&p2w,
                   (void*)&p1n, (void*)&xtb, (void*)&S1,
                   (void*)&h1, (void*)&S1, (void*)&prog, (void*)&prep_done };
  hipLaunchCooperativeKernel((void*)k_pre2, dim3(256), dim3(512), args, 0, stream);

  k_gemm2<<<256, 512, 0, stream>>>((const __hip_bfloat16*)h1, w2, g1, b1, S1, S2, hmax, hmin);
  k_pool<<<256, 256, 0, stream>>>(hmax, hmin, g2, b2, S2, out1);
}